// Round 1
// 840.267 us; speedup vs baseline: 1.1274x; 1.1274x over previous
//
#include <hip/hip_runtime.h>
#include <stdint.h>

// ============================================================================
// Windowed attention (SAM-style), MI355X gfx950.
// B=256, N=196 (14x14), C=768, 12 heads x 64.
// R1: attn wave-independent (unchanged this round).
// R2: GEMMs rewritten as 256x256-tile / BK=64 / 8-wave / double-buffered
//     8-phase schedule (T1 XCD swizzle + T2 LDS XOR-swizzle + T3/T4 early
//     counted staging + T5 setprio). Replaces the m97-style 128^2 kernel
//     that was barrier-drain bound (MfmaUtil 24%, 2.2e7 bank conflicts).
// ============================================================================

typedef __attribute__((ext_vector_type(8))) short bf16x8;   // 8 bf16 = 4 VGPRs
typedef __attribute__((ext_vector_type(4))) float f32x4;
typedef unsigned short u16;
typedef unsigned int u32;

__device__ __forceinline__ u16 f2bf(float f) {
  u32 x = __float_as_uint(f);
  x += 0x7fffu + ((x >> 16) & 1u);   // round-to-nearest-even
  return (u16)(x >> 16);
}

__device__ __forceinline__ void gload_lds16(const void* g, void* l) {
  __builtin_amdgcn_global_load_lds(
      (__attribute__((address_space(1))) void*)g,
      (__attribute__((address_space(3))) void*)l, 16, 0, 0);
}

// ---------------------------------------------------------------------------
__global__ __launch_bounds__(256) void cvt_bf16(const float* __restrict__ src,
                                                u16* __restrict__ dst, int n4) {
  int i = blockIdx.x * 256 + threadIdx.x;
  if (i < n4) {
    float4 f = ((const float4*)src)[i];
    uint2 p;
    p.x = (u32)f2bf(f.x) | ((u32)f2bf(f.y) << 16);
    p.y = (u32)f2bf(f.z) | ((u32)f2bf(f.w) << 16);
    ((uint2*)dst)[i] = p;
  }
}

// ---------------------------------------------------------------------------
// 256x256-tile bf16 GEMM, BK=64, K=768 (12 K-tiles), B^T weights.
// 512 threads = 8 waves (2 M x 4 N); per-wave output 128x64.
// LDS 128 KiB: 2 dbuf x (A 256x64 + B 256x64) bf16, XOR-swizzled at 16B
// chunk granularity: chunk (row, s) holds logical col8 = s ^ (row & 7).
// global_load_lds writes linearly; the global SOURCE address is
// inverse-swizzled (rule #21: both-sides-or-neither).
//
// Per K-tile, 4 phases; phase = {ds_read subtile, (P0: stage next tile,
// 8 x global_load_lds_dwordx4), barrier, lgkmcnt(0), setprio(1), 16 MFMA,
// setprio(0), barrier}. Only vmcnt wait is at tile end (P3), ~3 phases
// after issue. WAR safety: every phase drains its own ds_reads (lgkmcnt(0))
// before its MFMA, and the P3 trailing barrier orders all reads of the
// next-staged buffer before any wave issues stores into it.
__device__ __forceinline__ void stage8(const u16* pA, const u16* pB,
                                       char* dstA, int k0) {
#pragma unroll
  for (int i = 0; i < 4; i++)
    gload_lds16(pA + (size_t)i * 49152 + k0, dstA + i * 8192);
#pragma unroll
  for (int i = 0; i < 4; i++)
    gload_lds16(pB + (size_t)i * 49152 + k0, dstA + 32768 + i * 8192);
}

template <int MODE, int NT>
__global__ __launch_bounds__(512, 2) void gemm256(
    const u16* __restrict__ A, const u16* __restrict__ W,
    const float* __restrict__ bias, u16* __restrict__ qb, u16* __restrict__ kb,
    u16* __restrict__ vb, float* __restrict__ outf) {
  __shared__ char lds[131072];   // 2 x (32KB A + 32KB B)

  const int t = threadIdx.x;
  const int lane = t & 63, wv = t >> 6;
  const int quad = lane >> 4, l15 = lane & 15;
  const int wm = wv >> 2, wn = wv & 3;   // 2 x 4 wave grid

  // ---- bijective XCD-chunked block swizzle (m204), n-tile fastest ----
  const u32 nwg = gridDim.x;
  const u32 wg = blockIdx.x;
  const u32 qd = nwg >> 3, rm = nwg & 7;
  const u32 xcd = wg & 7, loc = wg >> 3;
  const u32 swz = (xcd < rm) ? (xcd * (qd + 1) + loc)
                             : (rm * (qd + 1) + (xcd - rm) * qd + loc);
  const int mtile = swz / NT;
  const int ntile = (int)swz - mtile * NT;
  const int m0 = mtile << 8, n0 = ntile << 8;

  // ---- staging addresses (thread-constant swizzle) ----
  // chunk c = i*512 + t: row = t>>3 + i*64, s = t&7; logical col8 = s^(row&7)
  const int srow = t >> 3;
  const int scol = ((t & 7) ^ (srow & 7)) << 3;   // elements
  const u16* pA = A + (size_t)(m0 + srow) * 768 + scol;
  const u16* pB = W + (size_t)(n0 + srow) * 768 + scol;
  char* sdst = lds + t * 16;

  // ---- ds_read byte offsets (within current buffer) ----
  const int swz0 = ((quad) ^ (l15 & 7)) << 4;        // k-step 0
  const int swz1 = ((4 + quad) ^ (l15 & 7)) << 4;    // k-step 1
  const int arow = (wm * 128 + l15) * 128;
  const int brow = 32768 + (wn * 64 + l15) * 128;

  f32x4 acc[8][4];
#pragma unroll
  for (int i = 0; i < 8; i++)
#pragma unroll
    for (int j = 0; j < 4; j++) acc[i][j] = (f32x4){0.f, 0.f, 0.f, 0.f};

  // ---- prologue: stage tile 0 ----
  stage8(pA, pB, sdst, 0);
  asm volatile("s_waitcnt vmcnt(0)" ::: "memory");
  __builtin_amdgcn_s_barrier();

  bf16x8 af[4][2], bfr[4][2];
  for (int kt = 0; kt < 12; ++kt) {
    char* bufc = lds + ((kt & 1) << 16);
    char* nsdst = sdst + (((kt & 1) ^ 1) << 16);
    const int k0n = (kt + 1) << 6;

    // ======== P0: A rows 0-63 + B cols 0-31; stage next tile ========
#pragma unroll
    for (int mf = 0; mf < 4; mf++) {
      af[mf][0] = *(const bf16x8*)(bufc + arow + mf * 2048 + swz0);
      af[mf][1] = *(const bf16x8*)(bufc + arow + mf * 2048 + swz1);
    }
#pragma unroll
    for (int nf = 0; nf < 2; nf++) {
      bfr[nf][0] = *(const bf16x8*)(bufc + brow + nf * 2048 + swz0);
      bfr[nf][1] = *(const bf16x8*)(bufc + brow + nf * 2048 + swz1);
    }
    if (kt < 11) stage8(pA, pB, nsdst, k0n);
    __builtin_amdgcn_s_barrier();
    asm volatile("s_waitcnt lgkmcnt(0)" ::: "memory");
    __builtin_amdgcn_s_setprio(1);
#pragma unroll
    for (int k = 0; k < 2; k++)
#pragma unroll
      for (int mf = 0; mf < 4; mf++)
#pragma unroll
        for (int nf = 0; nf < 2; nf++)
          acc[mf][nf] = __builtin_amdgcn_mfma_f32_16x16x32_bf16(
              af[mf][k], bfr[nf][k], acc[mf][nf], 0, 0, 0);
    __builtin_amdgcn_s_setprio(0);
    __builtin_amdgcn_s_barrier();

    // ======== P1: B cols 32-63 ========
#pragma unroll
    for (int nf = 2; nf < 4; nf++) {
      bfr[nf][0] = *(const bf16x8*)(bufc + brow + nf * 2048 + swz0);
      bfr[nf][1] = *(const bf16x8*)(bufc + brow + nf * 2048 + swz1);
    }
    __builtin_amdgcn_s_barrier();
    asm volatile("s_waitcnt lgkmcnt(0)" ::: "memory");
    __builtin_amdgcn_s_setprio(1);
#pragma unroll
    for (int k = 0; k < 2; k++)
#pragma unroll
      for (int mf = 0; mf < 4; mf++)
#pragma unroll
        for (int nf = 2; nf < 4; nf++)
          acc[mf][nf] = __builtin_amdgcn_mfma_f32_16x16x32_bf16(
              af[mf][k], bfr[nf][k], acc[mf][nf], 0, 0, 0);
    __builtin_amdgcn_s_setprio(0);
    __builtin_amdgcn_s_barrier();

    // ======== P2: A rows 64-127 ========
#pragma unroll
    for (int mf = 0; mf < 4; mf++) {
      af[mf][0] = *(const bf16x8*)(bufc + arow + (mf + 4) * 2048 + swz0);
      af[mf][1] = *(const bf16x8*)(bufc + arow + (mf + 4) * 2048 + swz1);
    }
    __builtin_amdgcn_s_barrier();
    asm volatile("s_waitcnt lgkmcnt(0)" ::: "memory");
    __builtin_amdgcn_s_setprio(1);
#pragma unroll
    for (int k = 0; k < 2; k++)
#pragma unroll
      for (int mf = 0; mf < 4; mf++)
#pragma unroll
        for (int nf = 0; nf < 2; nf++)
          acc[mf + 4][nf] = __builtin_amdgcn_mfma_f32_16x16x32_bf16(
              af[mf][k], bfr[nf][k], acc[mf + 4][nf], 0, 0, 0);
    __builtin_amdgcn_s_setprio(0);
    __builtin_amdgcn_s_barrier();

    // ======== P3: no ds_reads; drain next-tile staging at the end ========
    __builtin_amdgcn_s_setprio(1);
#pragma unroll
    for (int k = 0; k < 2; k++)
#pragma unroll
      for (int mf = 0; mf < 4; mf++)
#pragma unroll
        for (int nf = 2; nf < 4; nf++)
          acc[mf + 4][nf] = __builtin_amdgcn_mfma_f32_16x16x32_bf16(
              af[mf][k], bfr[nf][k], acc[mf + 4][nf], 0, 0, 0);
    __builtin_amdgcn_s_setprio(0);
    asm volatile("s_waitcnt vmcnt(0)" ::: "memory");
    __builtin_amdgcn_s_barrier();
  }

  // ---- epilogue ----
  if (MODE == 0) {
    const int which = n0 / 768;   // block-uniform (256 | 768-boundaries)
    u16* dst = (which == 0) ? qb : ((which == 1) ? kb : vb);
    const float sc = (which == 0) ? 0.125f : 1.0f;
    float bs[4];
    size_t hb[4];
#pragma unroll
    for (int nf = 0; nf < 4; nf++) {
      int n = n0 + wn * 64 + nf * 16 + l15;
      int cc = n - which * 768;
      bs[nf] = bias[n];
      hb[nf] = (size_t)(cc >> 6) * 12544 + (size_t)(cc & 63);
    }
#pragma unroll
    for (int mf = 0; mf < 8; mf++) {
#pragma unroll
      for (int r = 0; r < 4; r++) {
        int m = m0 + wm * 128 + mf * 16 + (quad << 2) + r;
        int bb = m / 196;
        int tok = m - bb * 196;
        size_t rb = (size_t)bb * 150528 + (size_t)tok * 64;
#pragma unroll
        for (int nf = 0; nf < 4; nf++)
          dst[rb + hb[nf]] = f2bf((acc[mf][nf][r] + bs[nf]) * sc);
      }
    }
  } else {
    float bs[4];
#pragma unroll
    for (int nf = 0; nf < 4; nf++)
      bs[nf] = bias[n0 + wn * 64 + nf * 16 + l15];
#pragma unroll
    for (int mf = 0; mf < 8; mf++) {
#pragma unroll
      for (int r = 0; r < 4; r++) {
        int m = m0 + wm * 128 + mf * 16 + (quad << 2) + r;
#pragma unroll
        for (int nf = 0; nf < 4; nf++)
          outf[(size_t)m * 768 + (n0 + wn * 64 + nf * 16 + l15)] =
              acc[mf][nf][r] + bs[nf];
      }
    }
  }
}

// ---------------------------------------------------------------------------
// Fused attention, wave-independent q-tiles. One block per (b,h), 4 waves.
// (unchanged from R1)
__global__ __launch_bounds__(256) void attn_fused(
    const u16* __restrict__ qbuf, const u16* __restrict__ kbuf,
    const u16* __restrict__ vbuf, const float* __restrict__ rel_h,
    const float* __restrict__ rel_w, u16* __restrict__ aout) {
  __shared__ u16 Vt[26 * 512];        // 26 chunks x [64 d][8 keys]
  __shared__ u16 PsArr[4 * 26 * 128]; // per-wave: 26 chunks x [16 row][8 keys]

  const int t = threadIdx.x;
  const int bh = blockIdx.x;
  const int b = bh / 12, h = bh - b * 12;
  const int lane = t & 63, wv = t >> 6;
  const int quad = lane >> 4, l15 = lane & 15;
  const size_t base = (size_t)bh * (196 * 64);

  u16* Ps = PsArr + wv * (26 * 128);
  float* Tf = (float*)Ps;             // T bias union: 2 x [16][28] f32 = 3584 B

  // ---- stage V^T (chunked) ----
  for (int c = t; c < 196 * 8; c += 256) {
    int row = c >> 3, seg = c & 7;    // key row, d-segment
    uint4 vv = *(const uint4*)(vbuf + base + row * 64 + seg * 8);
    const u16* pv8 = (const u16*)&vv;
    u16* dst = Vt + (row >> 3) * 512 + (row & 7);
#pragma unroll
    for (int e = 0; e < 8; e++) dst[(seg * 8 + e) * 8] = pv8[e];
  }
  // zero keys 196..207 (chunks 24,25 tails) so PV never multiplies NaN bits
  for (int i = t; i < 12 * 64; i += 256) {
    int k = 196 + (i >> 6), d = i & 63;
    Vt[(k >> 3) * 512 + d * 8 + (k & 7)] = 0;
  }

  // ---- rel-pos B-frags (8): [half h/w][ntile][ks] ----
  bf16x8 brl[2][2][2];
#pragma unroll
  for (int half = 0; half < 2; half++) {
    const float* relp = half ? rel_w : rel_h;
#pragma unroll
    for (int nt = 0; nt < 2; nt++) {
      int ridx = nt * 16 + l15;
      if (ridx > 26) ridx = 26;       // dup; cols >=27 never read
#pragma unroll
      for (int ks = 0; ks < 2; ks++) {
        const float* p = relp + ridx * 64 + ks * 32 + quad * 8;
        float4 f0 = *(const float4*)p;
        float4 f1 = *(const float4*)(p + 4);
        bf16x8 r;
        r[0] = (short)f2bf(f0.x); r[1] = (short)f2bf(f0.y);
        r[2] = (short)f2bf(f0.z); r[3] = (short)f2bf(f0.w);
        r[4] = (short)f2bf(f1.x); r[5] = (short)f2bf(f1.y);
        r[6] = (short)f2bf(f1.z); r[7] = (short)f2bf(f1.w);
        brl[half][nt][ks] = r;
      }
    }
  }
  __syncthreads();   // Vt ready (only barrier)

  // ---- wave-independent q-tiles ----
  for (int qt = wv; qt < 13; qt += 4) {
    // Q A-frags (row-clamped)
    int qrl = qt * 16 + l15;
    if (qrl > 195) qrl = 195;
    bf16x8 aq0 = *(const bf16x8*)(qbuf + base + qrl * 64 + quad * 8);
    bf16x8 aq1 = *(const bf16x8*)(qbuf + base + qrl * 64 + 32 + quad * 8);

    // T bias: T[qrow][r27] = q . rel[r27], stored f32 in Ps union
#pragma unroll
    for (int half = 0; half < 2; half++) {
#pragma unroll
      for (int nt = 0; nt < 2; nt++) {
        f32x4 tc = (f32x4){0.f, 0.f, 0.f, 0.f};
        tc = __builtin_amdgcn_mfma_f32_16x16x32_bf16(aq0, brl[half][nt][0], tc, 0, 0, 0);
        tc = __builtin_amdgcn_mfma_f32_16x16x32_bf16(aq1, brl[half][nt][1], tc, 0, 0, 0);
        int col = nt * 16 + l15;
        if (col < 27) {
#pragma unroll
          for (int r = 0; r < 4; r++)
            Tf[half * 448 + (quad * 4 + r) * 28 + col] = tc[r];
        }
      }
    }

    // per-row h/w coords
    int trow[4], hqv[4], wqv[4];
#pragma unroll
    for (int r = 0; r < 4; r++) {
      int qr = qt * 16 + quad * 4 + r;
      if (qr > 195) qr = 195;
      hqv[r] = qr / 14;
      wqv[r] = qr - hqv[r] * 14;
      trow[r] = (quad * 4 + r) * 28;
    }

    // pass 1: scores + bias + exp (no max-sub: logits bounded), P in regs
    u32 pw2[13][2];
    float sm[4] = {0.f, 0.f, 0.f, 0.f};
#pragma unroll
    for (int kt = 0; kt < 13; kt++) {
      int key = kt * 16 + l15;
      int keyc = (key > 195) ? 195 : key;
      bool valid = (key < 196);
      bf16x8 bk0 = *(const bf16x8*)(kbuf + base + keyc * 64 + quad * 8);
      bf16x8 bk1 = *(const bf16x8*)(kbuf + base + keyc * 64 + 32 + quad * 8);
      f32x4 s = (f32x4){0.f, 0.f, 0.f, 0.f};
      s = __builtin_amdgcn_mfma_f32_16x16x32_bf16(aq0, bk0, s, 0, 0, 0);
      s = __builtin_amdgcn_mfma_f32_16x16x32_bf16(aq1, bk1, s, 0, 0, 0);
      int hk = keyc / 14, wk = keyc - hk * 14;
      float pr[4];
#pragma unroll
      for (int r = 0; r < 4; r++) {
        float v = s[r] + Tf[trow[r] + (hqv[r] - hk + 13)] +
                  Tf[448 + trow[r] + (wqv[r] - wk + 13)];
        float p = valid ? __expf(v) : 0.f;
        pr[r] = p;
        sm[r] += p;
      }
      pw2[kt][0] = (u32)f2bf(pr[0]) | ((u32)f2bf(pr[1]) << 16);
      pw2[kt][1] = (u32)f2bf(pr[2]) | ((u32)f2bf(pr[3]) << 16);
    }

    // row sums across the 16 lanes holding each row
#pragma unroll
    for (int r = 0; r < 4; r++) {
      sm[r] += __shfl_xor(sm[r], 1, 64);
      sm[r] += __shfl_xor(sm[r], 2, 64);
      sm[r] += __shfl_xor(sm[r], 4, 64);
      sm[r] += __shfl_xor(sm[r], 8, 64);
    }
    float inv[4];
#pragma unroll
    for (int r = 0; r < 4; r++) inv[r] = 1.0f / sm[r];

    // pass 2: P -> LDS (chunked A-layout); overwrites T (all T reads done)
#pragma unroll
    for (int kt = 0; kt < 13; kt++) {
      u16* pp = Ps + (kt * 2 + (l15 >> 3)) * 128 + (l15 & 7);
      pp[(quad * 4 + 0) * 8] = (u16)(pw2[kt][0] & 0xffff);
      pp[(quad * 4 + 1) * 8] = (u16)(pw2[kt][0] >> 16);
      pp[(quad * 4 + 2) * 8] = (u16)(pw2[kt][1] & 0xffff);
      pp[(quad * 4 + 3) * 8] = (u16)(pw2[kt][1] >> 16);
    }

    // PV: O[16q x 64d], K-steps of 32 keys; step 6 half-masked (keys 208+)
    f32x4 oacc[4];
#pragma unroll
    for (int dt = 0; dt < 4; dt++) oacc[dt] = (f32x4){0.f, 0.f, 0.f, 0.f};
#pragma unroll
    for (int ks = 0; ks < 7; ks++) {
      bool mvalid = (ks < 6) || (quad < 2);
      bf16x8 ap = (bf16x8){0, 0, 0, 0, 0, 0, 0, 0};
      if (mvalid) ap = *(const bf16x8*)(Ps + (ks * 4 + quad) * 128 + l15 * 8);
#pragma unroll
      for (int dt = 0; dt < 4; dt++) {
        bf16x8 bv = (bf16x8){0, 0, 0, 0, 0, 0, 0, 0};
        if (mvalid)
          bv = *(const bf16x8*)(Vt + (ks * 4 + quad) * 512 + (dt * 16 + l15) * 8);
        oacc[dt] = __builtin_amdgcn_mfma_f32_16x16x32_bf16(ap, bv, oacc[dt], 0, 0, 0);
      }
    }

    // normalize + store [B,N,C] bf16
#pragma unroll
    for (int dt = 0; dt < 4; dt++) {
#pragma unroll
      for (int r = 0; r < 4; r++) {
        int qrow = qt * 16 + quad * 4 + r;
        if (qrow < 196) {
          float val = oacc[dt][r] * inv[r];
          aout[((size_t)(b * 196 + qrow) * 12 + h) * 64 + dt * 16 + l15] = f2bf(val);
        }
      }
    }
  }
}

// ---------------------------------------------------------------------------
extern "C" void kernel_launch(void* const* d_in, const int* in_sizes, int n_in,
                              void* d_out, int out_size, void* d_ws, size_t ws_size,
                              hipStream_t stream) {
  (void)in_sizes; (void)n_in; (void)out_size; (void)ws_size;
  const float* x      = (const float*)d_in[0];
  const float* qkv_w  = (const float*)d_in[1];
  const float* qkv_b  = (const float*)d_in[2];
  const float* rel_h  = (const float*)d_in[3];
  const float* rel_w  = (const float*)d_in[4];
  const float* proj_w = (const float*)d_in[5];
  const float* proj_b = (const float*)d_in[6];
  float* out = (float*)d_out;

  char* ws = (char*)d_ws;
  u16* xbf  = (u16*)(ws);              // aliased: x_bf16, then attn_out
  u16* qbuf = (u16*)(ws + 77070336);
  u16* kbuf = (u16*)(ws + 154140672);
  u16* vbuf = (u16*)(ws + 231211008);
  u16* wqb  = (u16*)(ws + 308281344);
  u16* wpb  = (u16*)(ws + 311820288);

  cvt_bf16<<<37632, 256, 0, stream>>>(x, xbf, 38535168 / 4);
  cvt_bf16<<<1728, 256, 0, stream>>>(qkv_w, wqb, 1769472 / 4);
  cvt_bf16<<<576, 256, 0, stream>>>(proj_w, wpb, 589824 / 4);

  // QKV: M=50176 (196 tiles), N=2304 (9 tiles), K=768
  gemm256<0, 9><<<1764, 512, 0, stream>>>(xbf, wqb, qkv_b, qbuf, kbuf, vbuf,
                                          nullptr);
  attn_fused<<<3072, 256, 0, stream>>>(qbuf, kbuf, vbuf, rel_h, rel_w, xbf);
  // proj: N=768 (3 tiles)
  gemm256<1, 3><<<588, 512, 0, stream>>>(xbf, wpb, proj_b, nullptr, nullptr,
                                         nullptr, out);
}